// Round 5
// baseline (224.404 us; speedup 1.0000x reference)
//
#include <hip/hip_runtime.h>

// Problem constants (reference: B=32, S=4096, D=256, float32)
constexpr int S_LEN = 4096;
constexpr int D_DIM = 256;
constexpr int ROWS_PER_WAVE = 4;

// ---------------------------------------------------------------------------
// Kernel 1: per-batch scan producing a pre-encoded output-row index.
//   orow_enc[b][t] =  pos[t]                 if keep   (>= 0)
//                  =  ~(cnt + (t - pos[t]))  if drop   (< 0)
// One block (1024 threads) per batch row; each thread owns 4 mask elements.
// ---------------------------------------------------------------------------
__global__ __launch_bounds__(1024)
void scan_kernel(const int* __restrict__ mask,
                 int* __restrict__ orow_enc) {
    const int b   = blockIdx.x;
    const int tid = threadIdx.x;           // 0..1023
    const int lane = tid & 63;
    const int wid  = tid >> 6;             // 0..15
    __shared__ int wtot[16];

    const int base = b * S_LEN + tid * 4;
    int4 m = *reinterpret_cast<const int4*>(mask + base);
    int v[4] = {m.x, m.y, m.z, m.w};
    const int tot = v[0] + v[1] + v[2] + v[3];

    // wave-64 inclusive scan of per-thread totals
    int scan = tot;
#pragma unroll
    for (int off = 1; off < 64; off <<= 1) {
        int n = __shfl_up(scan, off, 64);
        if (lane >= off) scan += n;
    }
    if (lane == 63) wtot[wid] = scan;
    __syncthreads();

    int wexcl = 0, cnt = 0;
#pragma unroll
    for (int i = 0; i < 16; ++i) {
        int w = wtot[i];
        if (i < wid) wexcl += w;
        cnt += w;
    }

    // exclusive prefix at this thread's first element
    int excl = wexcl + (scan - tot);

    int4 e;
    int t = tid * 4;
    e.x = v[0] ? excl : ~(cnt + (t + 0 - excl)); excl += v[0];
    e.y = v[1] ? excl : ~(cnt + (t + 1 - excl)); excl += v[1];
    e.z = v[2] ? excl : ~(cnt + (t + 2 - excl)); excl += v[2];
    e.w = v[3] ? excl : ~(cnt + (t + 3 - excl));
    *reinterpret_cast<int4*>(orow_enc + base) = e;
}

// ---------------------------------------------------------------------------
// Kernel 2: scatter. One wave per 4 consecutive timestep rows.
// Per wave: 1 broadcast int4 enc load, then 4 INDEPENDENT float4 loads
// (4 KiB in flight per wave -> 4x the memory-level parallelism of one-row-
// per-wave), then 4 float4 stores. Every output row written exactly once.
// ---------------------------------------------------------------------------
__global__ __launch_bounds__(256)
void scatter_kernel(const float* __restrict__ x,
                    const int* __restrict__ orow_enc,
                    float* __restrict__ out) {
    const int lane = threadIdx.x & 63;
    const int w    = blockIdx.x * 4 + (threadIdx.x >> 6); // global wave id
    const int r0   = w * ROWS_PER_WAVE;                   // first row (global)
    const int b    = r0 >> 12;                            // r0 / 4096
    const int t0   = r0 & (S_LEN - 1);

    // broadcast 16B load of the 4 encoded output rows
    int4 e4 = *reinterpret_cast<const int4*>(orow_enc + r0);
    int enc[ROWS_PER_WAVE] = {e4.x, e4.y, e4.z, e4.w};

    const float* xrow = x + ((size_t)b * S_LEN + t0) * D_DIM;

    // phase 1: issue all independent loads
    float4 vals[ROWS_PER_WAVE];
#pragma unroll
    for (int i = 0; i < ROWS_PER_WAVE; ++i) {
        vals[i] = make_float4(0.f, 0.f, 0.f, 0.f);
        if (enc[i] >= 0)
            vals[i] = reinterpret_cast<const float4*>(xrow + (size_t)i * D_DIM)[lane];
    }

    // phase 2: stores
    float* obase = out + (size_t)b * S_LEN * D_DIM;
#pragma unroll
    for (int i = 0; i < ROWS_PER_WAVE; ++i) {
        const int orow = (enc[i] >= 0) ? enc[i] : ~enc[i];
        reinterpret_cast<float4*>(obase + (size_t)orow * D_DIM)[lane] = vals[i];
    }
}

// ---------------------------------------------------------------------------
extern "C" void kernel_launch(void* const* d_in, const int* in_sizes, int n_in,
                              void* d_out, int out_size, void* d_ws, size_t ws_size,
                              hipStream_t stream) {
    const float* x    = (const float*)d_in[0];
    const int*   mask = (const int*)d_in[1];
    float*       out  = (float*)d_out;

    const int B = in_sizes[1] / S_LEN;     // 32

    int* orow_enc = (int*)d_ws;            // B*S ints = 512 KiB

    scan_kernel<<<B, 1024, 0, stream>>>(mask, orow_enc);

    const int waves  = (B * S_LEN) / ROWS_PER_WAVE;  // 8192 waves
    const int blocks = waves / 4;                    // 256-thread blocks, 4 waves each
    scatter_kernel<<<blocks, 256, 0, stream>>>(x, orow_enc, out);
}

// Round 7
// 221.550 us; speedup vs baseline: 1.0129x; 1.0129x over previous
//
#include <hip/hip_runtime.h>

// Problem constants (reference: B=32, S=4096, D=256, float32)
constexpr int S_LEN = 4096;
constexpr int D_DIM = 256;

// ---------------------------------------------------------------------------
// Kernel 1: per-batch scan producing a pre-encoded output-row index.
//   orow_enc[b][t] =  pos[t]                 if keep   (>= 0)
//                  =  ~(cnt + (t - pos[t]))  if drop   (< 0)
// One block (1024 threads) per batch row; each thread owns 4 mask elements.
// ---------------------------------------------------------------------------
__global__ __launch_bounds__(1024)
void scan_kernel(const int* __restrict__ mask,
                 int* __restrict__ orow_enc) {
    const int b   = blockIdx.x;
    const int tid = threadIdx.x;           // 0..1023
    const int lane = tid & 63;
    const int wid  = tid >> 6;             // 0..15
    __shared__ int wtot[16];

    const int base = b * S_LEN + tid * 4;
    int4 m = *reinterpret_cast<const int4*>(mask + base);
    int v[4] = {m.x, m.y, m.z, m.w};
    const int tot = v[0] + v[1] + v[2] + v[3];

    // wave-64 inclusive scan of per-thread totals
    int scan = tot;
#pragma unroll
    for (int off = 1; off < 64; off <<= 1) {
        int n = __shfl_up(scan, off, 64);
        if (lane >= off) scan += n;
    }
    if (lane == 63) wtot[wid] = scan;
    __syncthreads();

    int wexcl = 0, cnt = 0;
#pragma unroll
    for (int i = 0; i < 16; ++i) {
        int w = wtot[i];
        if (i < wid) wexcl += w;
        cnt += w;
    }

    // exclusive prefix at this thread's first element
    int excl = wexcl + (scan - tot);

    int4 e;
    int t = tid * 4;
    e.x = v[0] ? excl : ~(cnt + (t + 0 - excl)); excl += v[0];
    e.y = v[1] ? excl : ~(cnt + (t + 1 - excl)); excl += v[1];
    e.z = v[2] ? excl : ~(cnt + (t + 2 - excl)); excl += v[2];
    e.w = v[3] ? excl : ~(cnt + (t + 3 - excl));
    *reinterpret_cast<int4*>(orow_enc + base) = e;
}

// ---------------------------------------------------------------------------
// Kernel 2: scatter. One wave per timestep row; 64 lanes x float4 = 1 KiB row.
// Per wave: 1 broadcast int load + (kept ? 1 float4 load : 0) + 1 float4 store.
// Within a batch both front (kept) and tail (dropped) write cursors advance
// monotonically with t -> two sequential write streams per batch: near-ideal
// DRAM pattern. Every output row is written exactly once -> no memset needed.
// ---------------------------------------------------------------------------
__global__ __launch_bounds__(512)
void scatter_kernel(const float* __restrict__ x,
                    const int* __restrict__ orow_enc,
                    float* __restrict__ out) {
    const int lane = threadIdx.x & 63;
    const int w    = blockIdx.x * 8 + (threadIdx.x >> 6);  // global wave/row id
    const int b = w >> 12;                                 // w / 4096
    const int t = w & (S_LEN - 1);

    const int e    = orow_enc[w];          // broadcast load (all lanes same addr)
    const bool keep = (e >= 0);
    const int orow  = keep ? e : ~e;

    const size_t in_off  = ((size_t)b * S_LEN + t)    * D_DIM;
    const size_t out_off = ((size_t)b * S_LEN + orow) * D_DIM;

    float4 val = make_float4(0.f, 0.f, 0.f, 0.f);
    if (keep) val = reinterpret_cast<const float4*>(x + in_off)[lane];
    reinterpret_cast<float4*>(out + out_off)[lane] = val;
}

// ---------------------------------------------------------------------------
extern "C" void kernel_launch(void* const* d_in, const int* in_sizes, int n_in,
                              void* d_out, int out_size, void* d_ws, size_t ws_size,
                              hipStream_t stream) {
    const float* x    = (const float*)d_in[0];
    const int*   mask = (const int*)d_in[1];
    float*       out  = (float*)d_out;

    const int B = in_sizes[1] / S_LEN;     // 32

    int* orow_enc = (int*)d_ws;            // B*S ints = 512 KiB

    scan_kernel<<<B, 1024, 0, stream>>>(mask, orow_enc);

    const int rows = B * S_LEN;            // one wave per row, 8 waves per block
    scatter_kernel<<<rows / 8, 512, 0, stream>>>(x, orow_enc, out);
}